// Round 16
// baseline (183.450 us; speedup 1.0000x reference)
//
#include <hip/hip_runtime.h>

// SFM recurrent model via MFMA: B=2048, T=60, D=6, H=64, F=10, O=1.
//
// R1-R15 summary: best R12 = 73 us; band 73-111 across 14 structures.
// Facts: wall = max(serial-chain, busy); 1 barrier domain -> 45-51%
// busy (R12); 2 cross-block domains -> 69% busy but 2x work (R15 102us);
// same-wave static M+P interleave fails (R10). Untried: heterogeneous
// WAVES per SIMD inside one block.
// R16: producer/consumer wave specialization, anti-phase groups.
//   512 thr: waves 0-3 = M (gate w, A=U^T static, transposed GEMM,
//   k=64, 4 m-tiles; wave0 + fre), waves 4-7 = P (batch p, lane=hcol).
//   Groups A=b0..3, B=b4..7. Per step:
//     [M: z_B(s)   | P: h_A(s) <- z_A(s)]  barrier
//     [M: z_A(s+1) | P: h_B(s) <- z_B(s)]  barrier
//   Every phase: each SIMD has 1 M-wave + 1 P-wave, independent ->
//   HW interleaves MFMA and VALU pipes (m114). x@W+bias in P (fp32);
//   fre xf folded by M-wave0 into fb.
//
// Layouts (verified R12/R14): A[m=lane&15][k=q*8+j]; B[k=q*8+j][n=lane&15];
// C col=lane&15 (n: b 0-3 hi, 4-7 lo), row=q*4+reg (m: hcol in tile).

#define BB 2048
#define TT 60
#define DD 6
#define HH 64
#define FF 10
#define NB 8      // batches per block (2 groups of 4)

#define XCS 964   // xc per-batch stride in floats (60*16 + 4 pad)
#define HSK 72    // hsp row stride in shorts (24 rows: A hi0-3/lo4-7, B 8-15, zero 16-23)
#define ZS 68     // z stride per (gate,b) row in floats

typedef short bf16x8 __attribute__((ext_vector_type(8)));
typedef float f32x4  __attribute__((ext_vector_type(4)));

__device__ __forceinline__ unsigned short f2bf(float f) {
    union { float f; unsigned u; } v; v.f = f;
    unsigned r = v.u + 0x7fffu + ((v.u >> 16) & 1u);   // RNE
    return (unsigned short)(r >> 16);
}
__device__ __forceinline__ float bf2f(unsigned short b) {
    union { unsigned u; float f; } v; v.u = ((unsigned)b) << 16; return v.f;
}
__device__ __forceinline__ float hsig_f(float v) {
    return __builtin_amdgcn_fmed3f(fmaf(v, 0.16666666666666666f, 0.5f), 0.0f, 1.0f);
}
__device__ __forceinline__ float tanh_f(float x) {
    float xc = fminf(fmaxf(x, -12.0f), 12.0f);
    float e  = __builtin_amdgcn_exp2f(xc * 2.8853900817779268f); // 2*log2(e)
    return (e - 1.0f) * __builtin_amdgcn_rcpf(e + 1.0f);
}
__device__ __forceinline__ float uni(float v) {
    return __int_as_float(__builtin_amdgcn_readfirstlane(__float_as_int(v)));
}
__device__ __forceinline__ void pinv(bf16x8& v) { asm volatile("" : "+v"(v)); }

__global__ __launch_bounds__(512, 1)
void sfm_kernel(
    const float* __restrict__ x,
    const float* __restrict__ W_i,  const float* __restrict__ U_i,  const float* __restrict__ b_i,
    const float* __restrict__ W_ste,const float* __restrict__ U_ste,const float* __restrict__ b_ste,
    const float* __restrict__ W_fre,const float* __restrict__ U_fre,const float* __restrict__ b_fre,
    const float* __restrict__ W_c,  const float* __restrict__ U_c,  const float* __restrict__ b_c,
    const float* __restrict__ W_o,  const float* __restrict__ U_o,  const float* __restrict__ b_o,
    const float* __restrict__ U_a,  const float* __restrict__ b_a,
    const float* __restrict__ W_p,  const float* __restrict__ b_p,
    float* __restrict__ out)
{
    const int tid  = threadIdx.x;
    const int lane = tid & 63;
    const int wave = tid >> 6;      // 0-3 = M (gate), 4-7 = P (batch)
    const int q    = lane >> 4;     // quad 0..3
    const int n16  = lane & 15;
    const int b0   = blockIdx.x * NB;

    __shared__ __align__(16) float xc[NB * XCS];            // [b][s][0..5]=x fp32, [6..15]=xf
    __shared__ __align__(16) unsigned short hsp[24 * HSK];  // A: hi 0-3, lo 4-7; B: 8-15; zero 16-23
    __shared__ __align__(16) float zA[4 * 4 * ZS];          // [gate*4+b][hcol] group A
    __shared__ __align__(16) float zB[4 * 4 * ZS];          // group B
    __shared__ __align__(16) float fbA[4 * 12];             // fre z (+xf) group A [b][f]
    __shared__ __align__(16) float fbB[4 * 12];
    __shared__ __align__(16) float ctab[10 * 10 * 2];
    __shared__ float cstabB[10 * 2];

    // ---- init: stage x fp32 coalesced, trig tables, zero h ----
    for (int i = tid; i < NB * TT * DD; i += 512) {
        const int b = i / (TT * DD), rem = i - b * (TT * DD);
        const int s = rem / DD, d = rem - s * DD;
        xc[b * XCS + s * 16 + d] = x[(size_t)b0 * (TT * DD) + i];
    }
    if (tid < 10) {
        const float CTc[10] = { 1.0f,  0.8090169943749475f,  0.30901699437494745f,
                               -0.30901699437494745f, -0.8090169943749475f, -1.0f,
                               -0.8090169943749475f, -0.30901699437494745f,
                                0.30901699437494745f,  0.8090169943749475f };
        const float STc[10] = { 0.0f,  0.5877852522924731f,  0.9510565162951535f,
                                0.9510565162951535f,  0.5877852522924731f,  0.0f,
                               -0.5877852522924731f, -0.9510565162951535f,
                               -0.9510565162951535f, -0.5877852522924731f };
        float cc = 0.0f, ss = 0.0f;
        #pragma unroll
        for (int j = 0; j < 10; ++j) if (tid == j) { cc = CTc[j]; ss = STc[j]; }
        cstabB[tid * 2] = cc; cstabB[tid * 2 + 1] = ss;
    }
    for (int i = tid; i < 24 * HSK; i += 512) hsp[i] = 0;   // rows 16-23 stay zero
    __syncthreads();

    // xf[b][s][f] = b_fre + x@W_fre; full ctab
    if (tid < NB * TT) {
        const int b = tid / TT, s = tid - b * TT;
        float xr[DD];
        #pragma unroll
        for (int d = 0; d < DD; ++d) xr[d] = xc[b * XCS + s * 16 + d];
        #pragma unroll
        for (int f = 0; f < FF; ++f) {
            float v = b_fre[f];
            #pragma unroll
            for (int d = 0; d < DD; ++d) v = fmaf(xr[d], W_fre[d * FF + f], v);
            xc[b * XCS + s * 16 + 6 + f] = v;
        }
    }
    if (tid < 100) {
        const int mm = tid / 10, ff = tid - mm * 10;
        const int idx = (ff * mm) % 10;
        ctab[tid * 2]     = cstabB[idx * 2];
        ctab[tid * 2 + 1] = cstabB[idx * 2 + 1];
    }

    if (wave < 4) {
        // ================= M-WAVE: gate = wave =================
        const int w = wave;
        const float* Ug = (w == 0) ? U_i : (w == 1) ? U_ste : (w == 2) ? U_c : U_o;

        // A-frags static: 4 m-tiles (hcol blocks), k=64 (2 chunks), Ah/Al
        bf16x8 Ah[4][2], Al[4][2], Fh[2], Fl[2];
        #pragma unroll
        for (int t = 0; t < 4; ++t) {
            #pragma unroll
            for (int c = 0; c < 2; ++c) {
                #pragma unroll
                for (int j = 0; j < 8; ++j) {
                    const int kv = c * 32 + q * 8 + j;
                    const float v = Ug[kv * HH + t * 16 + n16];
                    const unsigned short hb = f2bf(v);
                    Ah[t][c][j] = (short)hb;
                    Al[t][c][j] = (short)f2bf(v - bf2f(hb));
                }
                pinv(Ah[t][c]); pinv(Al[t][c]);
            }
        }
        #pragma unroll
        for (int c = 0; c < 2; ++c) {   // fre tile (used by wave 0 only)
            #pragma unroll
            for (int j = 0; j < 8; ++j) {
                const int kv = c * 32 + q * 8 + j;
                const float v = (n16 < FF) ? U_fre[kv * FF + n16] : 0.0f;
                const unsigned short hb = f2bf(v);
                Fh[c][j] = (short)hb;
                Fl[c][j] = (short)f2bf(v - bf2f(hb));
            }
            pinv(Fh[c]); pinv(Fl[c]);
        }

        // B-frag source rows per group: n16<8 -> group rows, else zero rows
        const unsigned short* hrpA = &hsp[((n16 < 8) ? n16       : (16 + n16 - 8)) * HSK];
        const unsigned short* hrpB = &hsp[((n16 < 8) ? (8 + n16) : (16 + n16 - 8)) * HSK];

        auto do_M = [&](const unsigned short* hrp, float* zg, float* fb,
                        const int gbase, const int s) {
            const bf16x8 B0 = *(const bf16x8*)&hrp[q * 8];
            const bf16x8 B1 = *(const bf16x8*)&hrp[32 + q * 8];
            #pragma unroll
            for (int t = 0; t < 4; ++t) {
                f32x4 a = {0.0f, 0.0f, 0.0f, 0.0f};
                a = __builtin_amdgcn_mfma_f32_16x16x32_bf16(Ah[t][0], B0, a, 0, 0, 0);
                a = __builtin_amdgcn_mfma_f32_16x16x32_bf16(Al[t][0], B0, a, 0, 0, 0);
                a = __builtin_amdgcn_mfma_f32_16x16x32_bf16(Ah[t][1], B1, a, 0, 0, 0);
                a = __builtin_amdgcn_mfma_f32_16x16x32_bf16(Al[t][1], B1, a, 0, 0, 0);
                f32x4 z;
                #pragma unroll
                for (int r = 0; r < 4; ++r)
                    z[r] = a[r] + __shfl_xor(a[r], 4, 64);   // fold hi(b)+lo(b+4)
                if (n16 < 4)
                    *(f32x4*)&zg[(w * 4 + n16) * ZS + t * 16 + q * 4] = z;
            }
            if (w == 0) {   // fre: zfre[f=q*4+r][b] + xf
                f32x4 a = {0.0f, 0.0f, 0.0f, 0.0f};
                a = __builtin_amdgcn_mfma_f32_16x16x32_bf16(Fh[0], B0, a, 0, 0, 0);
                a = __builtin_amdgcn_mfma_f32_16x16x32_bf16(Fl[0], B0, a, 0, 0, 0);
                a = __builtin_amdgcn_mfma_f32_16x16x32_bf16(Fh[1], B1, a, 0, 0, 0);
                a = __builtin_amdgcn_mfma_f32_16x16x32_bf16(Fl[1], B1, a, 0, 0, 0);
                f32x4 z;
                #pragma unroll
                for (int r = 0; r < 4; ++r)
                    z[r] = a[r] + __shfl_xor(a[r], 4, 64);
                if (n16 < 4) {
                    #pragma unroll
                    for (int r = 0; r < 4; ++r) {
                        const int f = q * 4 + r;
                        if (f < FF)
                            fb[n16 * 12 + f] = z[r] + xc[(gbase + n16) * XCS + s * 16 + 6 + f];
                    }
                }
            }
        };

        // prologue: z_A(0) from h=0
        do_M(hrpA, zA, fbA, 0, 0);
        __syncthreads();

        for (int s = 0; s < TT; ++s) {
            do_M(hrpB, zB, fbB, 4, s);          // phase 1: z_B(s)
            __syncthreads();
            if (s + 1 < TT)
                do_M(hrpA, zA, fbA, 0, s + 1);  // phase 2: z_A(s+1)
            __syncthreads();
        }
    } else {
        // ================= P-WAVE: batch = wave-4, lane = hcol =================
        const int p  = wave - 4;
        const int hc = lane;
        const float bav = b_a[hc];
        const float wpv = W_p[hc];
        const float bpv = uni(b_p[0]);
        float uav[FF];
        #pragma unroll
        for (int f = 0; f < FF; ++f) uav[f] = uni(U_a[f]);
        float wxi[DD], wxs[DD], wxc[DD], wxo[DD];
        #pragma unroll
        for (int d = 0; d < DD; ++d) {
            wxi[d] = W_i[d * HH + hc];  wxs[d] = W_ste[d * HH + hc];
            wxc[d] = W_c[d * HH + hc];  wxo[d] = W_o[d * HH + hc];
        }
        const float bi = b_i[hc], bs = b_ste[hc], bc = b_c[hc], bo = b_o[hc];

        float SreA[FF], SimA[FF], SreB[FF], SimB[FF];
        #pragma unroll
        for (int f = 0; f < FF; ++f) { SreA[f]=0.f; SimA[f]=0.f; SreB[f]=0.f; SimB[f]=0.f; }
        float hvA = 0.0f, hvB = 0.0f;

        auto do_P = [&](const float* zg, const float* fb, float* Sre, float* Sim,
                        const int bglob, const int grow, const int s,
                        const float* tp) -> float {
            const float* xr = &xc[bglob * XCS + s * 16];
            float vi = bi, vs = bs, vc = bc, vo = bo;
            #pragma unroll
            for (int d = 0; d < DD; ++d) {
                const float xd = xr[d];   // wave-uniform broadcast
                vi = fmaf(xd, wxi[d], vi);
                vs = fmaf(xd, wxs[d], vs);
                vc = fmaf(xd, wxc[d], vc);
                vo = fmaf(xd, wxo[d], vo);
            }
            const float zi = zg[(0 * 4 + p) * ZS + hc] + vi;
            const float zs = zg[(1 * 4 + p) * ZS + hc] + vs;
            const float zc = zg[(2 * 4 + p) * ZS + hc] + vc;
            const float zo = zg[(3 * 4 + p) * ZS + hc] + vo;

            float fr[FF];
            #pragma unroll
            for (int f = 0; f < FF; ++f) fr[f] = hsig_f(fb[p * 12 + f]);

            const float iv  = hsig_f(zi);
            const float stv = hsig_f(zs);
            const float ov  = hsig_f(zo);
            const float cv  = iv * tanh_f(zc);

            float a0 = bav, a1 = 0.0f;
            #pragma unroll
            for (int f = 0; f < FF; ++f) {
                const float2 tv = *(const float2*)&tp[f * 2];
                const float fc = stv * fr[f];
                Sre[f] = fmaf(fc, Sre[f], cv * tv.x);
                Sim[f] = fmaf(fc, Sim[f], cv * tv.y);
                const float A = fmaf(Sim[f], Sim[f], Sre[f] * Sre[f]);
                if (f & 1) a1 = fmaf(A, uav[f], a1);
                else       a0 = fmaf(A, uav[f], a0);
            }
            const float hv = ov * tanh_f(a0 + a1);
            const unsigned short hb = f2bf(hv);
            hsp[(grow + p) * HSK + hc]     = hb;
            hsp[(grow + 4 + p) * HSK + hc] = f2bf(hv - bf2f(hb));
            return hv;
        };

        __syncthreads();   // matches M prologue barrier

        int m = 1;  // (s+1) % 10
        for (int s = 0; s < TT; ++s) {
            const float* tp = &ctab[m * 20];
            hvA = do_P(zA, fbA, SreA, SimA, p, 0, s, tp);       // phase 1: h_A(s)
            __syncthreads();
            hvB = do_P(zB, fbB, SreB, SimB, 4 + p, 8, s, tp);   // phase 2: h_B(s)
            __syncthreads();
            if (++m == 10) m = 0;
        }

        // ---- output: out[b] = sum_hc h*W_p + b_p (P-waves only) ----
        float vA = hvA * wpv, vB = hvB * wpv;
        #pragma unroll
        for (int off = 32; off > 0; off >>= 1) {
            vA += __shfl_xor(vA, off, 64);
            vB += __shfl_xor(vB, off, 64);
        }
        if (lane == 0) {
            out[b0 + p]     = vA + bpv;
            out[b0 + 4 + p] = vB + bpv;
        }
        return;
    }
}

extern "C" void kernel_launch(void* const* d_in, const int* in_sizes, int n_in,
                              void* d_out, int out_size, void* d_ws, size_t ws_size,
                              hipStream_t stream) {
    (void)in_sizes; (void)n_in; (void)d_ws; (void)ws_size; (void)out_size;
    const float* x     = (const float*)d_in[0];
    const float* W_i   = (const float*)d_in[1];
    const float* U_i   = (const float*)d_in[2];
    const float* b_i   = (const float*)d_in[3];
    const float* W_ste = (const float*)d_in[4];
    const float* U_ste = (const float*)d_in[5];
    const float* b_ste = (const float*)d_in[6];
    const float* W_fre = (const float*)d_in[7];
    const float* U_fre = (const float*)d_in[8];
    const float* b_fre = (const float*)d_in[9];
    const float* W_c   = (const float*)d_in[10];
    const float* U_c   = (const float*)d_in[11];
    const float* b_c   = (const float*)d_in[12];
    const float* W_o   = (const float*)d_in[13];
    const float* U_o   = (const float*)d_in[14];
    const float* b_o   = (const float*)d_in[15];
    const float* U_a   = (const float*)d_in[16];
    const float* b_a   = (const float*)d_in[17];
    const float* W_p   = (const float*)d_in[18];
    const float* b_p   = (const float*)d_in[19];

    sfm_kernel<<<BB / NB, 512, 0, stream>>>(
        x, W_i, U_i, b_i, W_ste, U_ste, b_ste, W_fre, U_fre, b_fre,
        W_c, U_c, b_c, W_o, U_o, b_o, U_a, b_a, W_p, b_p, (float*)d_out);
}